// Round 1
// baseline (599.325 us; speedup 1.0000x reference)
//
#include <hip/hip_runtime.h>
#include <math.h>

// ---------------------------------------------------------------------------
// MambaAnglePredictor: fc -> in_proj -> conv+silu -> chunked SSM scan (SSD)
//   -> gate+RMSNorm -> out_proj -> MLP -> mean -> angle
// Round 1: correct fp32 pipeline, chunked scan Q=64, no MFMA yet.
// ---------------------------------------------------------------------------

#define BDIM 4
#define LDIM 4096
#define BL (BDIM*LDIM)      // 16384 tokens
#define DM 192
#define DIP 904
#define DI 384
#define DS 64
#define NH 8
#define HD 48
#define CONVD 512
#define QC 64               // chunk length
#define NC (LDIM/QC)        // 64 chunks
#define BH (BDIM*NH)        // 32

// workspace offsets (floats). total = 39,059,584 floats = 156.2 MB
#define OFF_H    0u          // 16384*192      (reused as h2 after scan)
#define OFF_Z    3145728u    // 16384*384
#define OFF_XBC  9437184u    // 16384*512      (reused as T after conv)
#define OFF_T    OFF_XBC     // 2048*3072
#define OFF_XS   17825792u   // 32*4096*48
#define OFF_BM   24117248u   // 16384*64
#define OFF_CM   25165824u   // 16384*64
#define OFF_DT   26214400u   // 32*4096
#define OFF_LAC  26345472u   // 2048*64
#define OFF_SP   26476544u   // 2048*3072
#define OFF_Y    32768000u   // 16384*384
#define OFF_MACC 39059456u   // 4*32
#define OFF_H2   OFF_H

__device__ __forceinline__ float sigmoidf_(float x){ return 1.0f/(1.0f+__expf(-x)); }

// --------------------------- K1: h = x@Wfc + bfc ---------------------------
__global__ void k_fc(const float* __restrict__ x, const float* __restrict__ Wfc,
                     const float* __restrict__ bfc, float* __restrict__ h){
  int bl = blockIdx.x; int d = threadIdx.x;
  float4 xv = *(const float4*)(x + bl*4);
  float acc = bfc[d];
  acc = fmaf(xv.x, Wfc[d], acc);
  acc = fmaf(xv.y, Wfc[192+d], acc);
  acc = fmaf(xv.z, Wfc[384+d], acc);
  acc = fmaf(xv.w, Wfc[576+d], acc);
  h[(size_t)bl*192 + d] = acc;
}

// ----------------- generic 128x128-tile fp32 GEMM, 8x8/thread --------------
// MODE 0: plain store to out (stride ND). MODE 1: in_proj split epilogue.
template<int KD, int ND, int MODE>
__global__ __launch_bounds__(256) void k_gemm(
    const float* __restrict__ A, const float* __restrict__ Bw,
    float* __restrict__ out,
    float* __restrict__ zbuf, float* __restrict__ xbc, float* __restrict__ dtbuf,
    const float* __restrict__ dt_bias, const float* __restrict__ A_log){
  __shared__ __align__(16) float sA[16][132];   // [kk][m]
  __shared__ __align__(16) float sB[16][132];   // [kk][n]
  int tid = threadIdx.x;
  int m0 = blockIdx.x*128, n0 = blockIdx.y*128;
  int ty = tid>>4, tx = tid&15;
  float acc[8][8];
  #pragma unroll
  for (int i=0;i<8;i++)
    #pragma unroll
    for (int j=0;j<8;j++) acc[i][j]=0.f;

  for (int k0=0;k0<KD;k0+=16){
    {
      int r = tid>>2, kc = (tid&3)*4;
      #pragma unroll
      for (int p=0;p<2;p++){
        int row = r + p*64;
        float4 v = *(const float4*)(A + (size_t)(m0+row)*KD + k0 + kc);
        sA[kc+0][row]=v.x; sA[kc+1][row]=v.y; sA[kc+2][row]=v.z; sA[kc+3][row]=v.w;
      }
      int kk = tid>>4, nc0 = (tid&15)*4;
      #pragma unroll
      for (int p=0;p<2;p++){
        int nc = nc0 + p*64;
        float4 v;
        if (n0+nc < ND) v = *(const float4*)(Bw + (size_t)(k0+kk)*ND + n0 + nc);
        else v = make_float4(0.f,0.f,0.f,0.f);
        *(float4*)&sB[kk][nc] = v;
      }
    }
    __syncthreads();
    #pragma unroll
    for (int kk=0;kk<16;kk++){
      float ar[8], br[8];
      *(float4*)&ar[0] = *(float4*)&sA[kk][ty*4];
      *(float4*)&ar[4] = *(float4*)&sA[kk][64+ty*4];
      *(float4*)&br[0] = *(float4*)&sB[kk][tx*4];
      *(float4*)&br[4] = *(float4*)&sB[kk][64+tx*4];
      #pragma unroll
      for (int i=0;i<8;i++)
        #pragma unroll
        for (int j=0;j<8;j++) acc[i][j] = fmaf(ar[i], br[j], acc[i][j]);
    }
    __syncthreads();
  }
  #pragma unroll
  for (int i=0;i<8;i++){
    int m = m0 + ((i<4)? ty*4+i : 64+ty*4+(i-4));
    #pragma unroll
    for (int j=0;j<8;j++){
      int n = n0 + ((j<4)? tx*4+j : 64+tx*4+(j-4));
      float v = acc[i][j];
      if (MODE==0){
        if (n < ND) out[(size_t)m*ND + n] = v;
      } else {
        if (n < 384){
          zbuf[(size_t)m*384 + n] = v;
        } else if (n < 896){
          xbc[(size_t)m*512 + (n-384)] = v;
        } else if (n < 904){
          int hh = n - 896;
          float xx = v + dt_bias[hh];
          float dtv = (xx > 20.f) ? xx : log1pf(__expf(xx));
          int b = m >> 12, l = m & 4095;
          dtbuf[(size_t)(b*8+hh)*4096 + l] = dtv;
        }
      }
    }
  }
}

// ------------------- K3: depthwise causal conv(4) + silu -------------------
__global__ void k_conv(const float* __restrict__ xbc, const float* __restrict__ conv_w,
                       const float* __restrict__ conv_b, float* __restrict__ xs,
                       float* __restrict__ Bm, float* __restrict__ Cm){
  int idx = blockIdx.x*256 + threadIdx.x;
  int bl = idx >> 9, c = idx & 511;
  int l = bl & 4095, b = bl >> 12;
  float acc = conv_b[c];
  #pragma unroll
  for (int k=0;k<4;k++){
    int ll = l - 3 + k;
    if (ll >= 0) acc = fmaf(conv_w[k*512+c], xbc[(size_t)(bl-3+k)*512 + c], acc);
  }
  float v = acc * sigmoidf_(acc);
  if (c < 384){
    int hh = c / 48, p = c - hh*48;
    xs[(size_t)((b*8+hh)*4096 + l)*48 + p] = v;
  } else if (c < 448){
    Bm[(size_t)bl*64 + (c-384)] = v;
  } else {
    Cm[(size_t)bl*64 + (c-448)] = v;
  }
}

// ----- K4 phase1: per-chunk cumlog(dA), chunk state T_k = sum w_s B_s x_s^T -----
__global__ __launch_bounds__(256) void k_phase1(
    const float* __restrict__ dtbuf, const float* __restrict__ Bm,
    const float* __restrict__ xs, const float* __restrict__ A_log,
    float* __restrict__ T, float* __restrict__ lac){
  __shared__ float sdt[64], sla[64], sw[64];
  __shared__ __align__(16) float sBW[64][64];
  __shared__ __align__(16) float sX[64][48];
  int tid = threadIdx.x, blk = blockIdx.x;
  int bh = blk >> 6, k = blk & 63;
  int b = bh >> 3, hh = bh & 7;
  int t0 = k*64;
  if (tid < 64) sdt[tid] = dtbuf[(size_t)bh*4096 + t0 + tid];
  __syncthreads();
  if (tid == 0){
    float eA = __expf(A_log[hh]);
    float cum = 0.f;
    for (int i=0;i<64;i++){ cum -= sdt[i]*eA; sla[i] = cum; }
  }
  __syncthreads();
  if (tid < 64){
    sw[tid] = __expf(sla[63]-sla[tid])*sdt[tid];
    lac[(size_t)blk*64 + tid] = sla[tid];
  }
  __syncthreads();
  {
    int s = tid>>2, n0 = (tid&3)*16;
    float wsc = sw[s];
    const float* src = Bm + (size_t)(b*4096 + t0 + s)*64 + n0;
    #pragma unroll
    for (int q=0;q<4;q++){
      float4 v = *(const float4*)(src + q*4);
      v.x*=wsc; v.y*=wsc; v.z*=wsc; v.w*=wsc;
      *(float4*)&sBW[s][n0+q*4] = v;
    }
    int p0 = (tid&3)*12;
    const float* xsrc = xs + (size_t)(bh*4096 + t0 + s)*48 + p0;
    #pragma unroll
    for (int q=0;q<3;q++) *(float4*)&sX[s][p0+q*4] = *(const float4*)(xsrc + q*4);
  }
  __syncthreads();
  if (tid < 192){
    int n0 = (tid/12)*4, p0 = (tid%12)*4;
    float acc[4][4];
    #pragma unroll
    for (int i=0;i<4;i++)
      #pragma unroll
      for (int j=0;j<4;j++) acc[i][j]=0.f;
    for (int s=0;s<64;s++){
      float bw[4], xv[4];
      *(float4*)bw = *(float4*)&sBW[s][n0];
      *(float4*)xv = *(float4*)&sX[s][p0];
      #pragma unroll
      for (int i=0;i<4;i++)
        #pragma unroll
        for (int j=0;j<4;j++) acc[i][j] = fmaf(bw[i], xv[j], acc[i][j]);
    }
    float* dst = T + (size_t)blk*3072;
    #pragma unroll
    for (int i=0;i<4;i++){
      float4 o; o.x=acc[i][0]; o.y=acc[i][1]; o.z=acc[i][2]; o.w=acc[i][3];
      *(float4*)(dst + (n0+i)*48 + p0) = o;
    }
  }
}

// ----- K5 phase2: sequential chunk-carry; stores S_prev per chunk -----
__global__ __launch_bounds__(1024) void k_phase2(
    const float* __restrict__ T, const float* __restrict__ lac, float* __restrict__ Sp){
  __shared__ float ssc[64];
  int tid = threadIdx.x, bh = blockIdx.x;
  if (tid < 64) ssc[tid] = __expf(lac[(size_t)(bh*64+tid)*64 + 63]);
  __syncthreads();
  const float* Tb = T + (size_t)bh*64*3072;
  float* Spb = Sp + (size_t)bh*64*3072;
  int e0 = tid, e1 = tid+1024, e2 = tid+2048;
  float s0=0.f,s1=0.f,s2=0.f;
  float n0 = Tb[e0], n1 = Tb[e1], n2 = Tb[e2];
  for (int k=0;k<64;k++){
    float c0=n0, c1=n1, c2=n2;
    if (k<63){
      const float* Tn = Tb + (size_t)(k+1)*3072;
      n0=Tn[e0]; n1=Tn[e1]; n2=Tn[e2];
    }
    float* Spk = Spb + (size_t)k*3072;
    Spk[e0]=s0; Spk[e1]=s1; Spk[e2]=s2;
    float sc = ssc[k];
    s0 = fmaf(sc,s0,c0); s1 = fmaf(sc,s1,c1); s2 = fmaf(sc,s2,c2);
  }
}

// ----- K6 phase3: Y = (L o C B^T) X + diag(exp(la)) C S_prev + D*x -----
__global__ __launch_bounds__(256) void k_phase3(
    const float* __restrict__ dtbuf, const float* __restrict__ lac,
    const float* __restrict__ Bm, const float* __restrict__ Cm,
    const float* __restrict__ xs, const float* __restrict__ Sp,
    const float* __restrict__ Dparam, float* __restrict__ y){
  __shared__ __align__(16) float sB[64][64];
  __shared__ __align__(16) float sC[64][64];
  __shared__ __align__(16) float sX[64][48];
  __shared__ __align__(16) float sSp[64][48];
  __shared__ __align__(16) float sGM[64][68];
  __shared__ float sdt[64], sla[64];
  int tid = threadIdx.x, blk = blockIdx.x;
  int bh = blk>>6, k = blk&63, b = bh>>3, hh = bh&7, t0 = k*64;
  if (tid < 64){
    sdt[tid] = dtbuf[(size_t)bh*4096 + t0 + tid];
    sla[tid] = lac[(size_t)blk*64 + tid];
  }
  {
    int s = tid>>2, n0 = (tid&3)*16;
    const float* bsrc = Bm + (size_t)(b*4096+t0+s)*64 + n0;
    const float* csrc = Cm + (size_t)(b*4096+t0+s)*64 + n0;
    #pragma unroll
    for (int q=0;q<4;q++){
      *(float4*)&sB[s][n0+q*4] = *(const float4*)(bsrc+q*4);
      *(float4*)&sC[s][n0+q*4] = *(const float4*)(csrc+q*4);
    }
    int p0 = (tid&3)*12;
    const float* xsrc = xs + (size_t)(bh*4096+t0+s)*48 + p0;
    const float* ssrc = Sp + (size_t)blk*3072 + s*48 + p0;
    #pragma unroll
    for (int q=0;q<3;q++){
      *(float4*)&sX[s][p0+q*4] = *(const float4*)(xsrc+q*4);
      *(float4*)&sSp[s][p0+q*4] = *(const float4*)(ssrc+q*4);
    }
  }
  __syncthreads();
  { // GM[i][s] = (s<=i) ? (C_i . B_s) * exp(la_i - la_s) * dt_s : 0
    int i0 = (tid>>4)*4, s0 = (tid&15)*4;
    float gm[4][4];
    #pragma unroll
    for (int i=0;i<4;i++)
      #pragma unroll
      for (int j=0;j<4;j++) gm[i][j]=0.f;
    if (s0 <= i0+3){
      for (int n4=0;n4<16;n4++){
        int n0 = n4*4;
        float cv[4][4], bv[4][4];
        #pragma unroll
        for (int ii=0;ii<4;ii++) *(float4*)cv[ii] = *(float4*)&sC[i0+ii][n0];
        #pragma unroll
        for (int ss=0;ss<4;ss++) *(float4*)bv[ss] = *(float4*)&sB[s0+ss][n0];
        #pragma unroll
        for (int ii=0;ii<4;ii++)
          #pragma unroll
          for (int ss=0;ss<4;ss++)
            #pragma unroll
            for (int q=0;q<4;q++) gm[ii][ss] = fmaf(cv[ii][q], bv[ss][q], gm[ii][ss]);
      }
      #pragma unroll
      for (int ii=0;ii<4;ii++)
        #pragma unroll
        for (int ss=0;ss<4;ss++){
          int i = i0+ii, s = s0+ss;
          gm[ii][ss] = (s<=i) ? gm[ii][ss]*__expf(sla[i]-sla[s])*sdt[s] : 0.f;
        }
    }
    #pragma unroll
    for (int ii=0;ii<4;ii++){
      float4 o; o.x=gm[ii][0]; o.y=gm[ii][1]; o.z=gm[ii][2]; o.w=gm[ii][3];
      *(float4*)&sGM[i0+ii][s0] = o;
    }
  }
  __syncthreads();
  if (tid < 192){
    int i0 = (tid/12)*4, p0 = (tid%12)*4;
    float fa[4][4], ia[4][4];
    #pragma unroll
    for (int i=0;i<4;i++)
      #pragma unroll
      for (int j=0;j<4;j++){ fa[i][j]=0.f; ia[i][j]=0.f; }
    for (int s4=0; s4<=(i0>>2); s4++){
      int s0 = s4*4;
      float g[4][4], xv[4][4];
      #pragma unroll
      for (int ii=0;ii<4;ii++) *(float4*)g[ii] = *(float4*)&sGM[i0+ii][s0];
      #pragma unroll
      for (int q=0;q<4;q++) *(float4*)xv[q] = *(float4*)&sX[s0+q][p0];
      #pragma unroll
      for (int ii=0;ii<4;ii++)
        #pragma unroll
        for (int q=0;q<4;q++)
          #pragma unroll
          for (int j=0;j<4;j++) fa[ii][j] = fmaf(g[ii][q], xv[q][j], fa[ii][j]);
    }
    for (int n4=0;n4<16;n4++){
      int n0 = n4*4;
      float cv[4][4], sp[4][4];
      #pragma unroll
      for (int ii=0;ii<4;ii++) *(float4*)cv[ii] = *(float4*)&sC[i0+ii][n0];
      #pragma unroll
      for (int q=0;q<4;q++) *(float4*)sp[q] = *(float4*)&sSp[n0+q][p0];
      #pragma unroll
      for (int ii=0;ii<4;ii++)
        #pragma unroll
        for (int q=0;q<4;q++)
          #pragma unroll
          for (int j=0;j<4;j++) ia[ii][j] = fmaf(cv[ii][q], sp[q][j], ia[ii][j]);
    }
    float Dh = Dparam[hh];
    #pragma unroll
    for (int ii=0;ii<4;ii++){
      int i = i0+ii;
      float ci = __expf(sla[i]);
      float4 xd = *(float4*)&sX[i][p0];
      float4 o;
      o.x = fa[ii][0] + ci*ia[ii][0] + Dh*xd.x;
      o.y = fa[ii][1] + ci*ia[ii][1] + Dh*xd.y;
      o.z = fa[ii][2] + ci*ia[ii][2] + Dh*xd.z;
      o.w = fa[ii][3] + ci*ia[ii][3] + Dh*xd.w;
      *(float4*)(y + (size_t)(b*4096+t0+i)*384 + hh*48 + p0) = o;
    }
  }
}

// ----- K7a: v = y*silu(z); RMSNorm*norm_w, in-place into y -----
__global__ __launch_bounds__(384) void k_gate(
    const float* __restrict__ zbuf, const float* __restrict__ norm_w, float* __restrict__ y){
  __shared__ float sred[6];
  __shared__ float srms;
  int bl = blockIdx.x, tid = threadIdx.x;
  float yv = y[(size_t)bl*384 + tid];
  float zv = zbuf[(size_t)bl*384 + tid];
  float g = yv * (zv * sigmoidf_(zv));
  float ss = g*g;
  #pragma unroll
  for (int off=32; off>0; off>>=1) ss += __shfl_xor(ss, off);
  if ((tid&63)==0) sred[tid>>6] = ss;
  __syncthreads();
  if (tid==0){
    float t=0.f;
    #pragma unroll
    for (int i=0;i<6;i++) t += sred[i];
    srms = rsqrtf(t*(1.f/384.f) + 1e-5f);
  }
  __syncthreads();
  y[(size_t)bl*384 + tid] = g * srms * norm_w[tid];
}

// ----- K8: MLP (192->32 relu, 32->32 relu) + partial mean accumulation -----
__global__ __launch_bounds__(256) void k_mlp(
    const float* __restrict__ h2, const float* __restrict__ W1, const float* __restrict__ b1,
    const float* __restrict__ W2, const float* __restrict__ b2, float* __restrict__ macc){
  __shared__ __align__(16) float sh2[32][192];
  __shared__ __align__(16) float sW1[192][32];
  __shared__ __align__(16) float sm1[32][32];
  __shared__ __align__(16) float sW2[32][32];
  __shared__ __align__(16) float sm2[32][32];
  int tid = threadIdx.x;
  int tok0 = blockIdx.x*32;
  int b = tok0 >> 12;
  #pragma unroll
  for (int r=0;r<6;r++){
    int e4 = tid + r*256;
    int row = e4/48, c4 = (e4%48)*4;
    *(float4*)&sh2[row][c4] = *(const float4*)(h2 + (size_t)(tok0+row)*192 + c4);
  }
  #pragma unroll
  for (int r=0;r<6;r++){
    int e4 = tid + r*256;
    int row = e4>>3, c4 = (e4&7)*4;
    *(float4*)&sW1[row][c4] = *(const float4*)(W1 + row*32 + c4);
  }
  {
    int row = tid>>3, c4 = (tid&7)*4;
    *(float4*)&sW2[row][c4] = *(const float4*)(W2 + row*32 + c4);
  }
  __syncthreads();
  {
    int tok = tid>>3, j0 = (tid&7)*4;
    float a0[4];
    #pragma unroll
    for (int j=0;j<4;j++) a0[j] = b1[j0+j];
    for (int kk=0;kk<192;kk++){
      float a = sh2[tok][kk];
      float w[4]; *(float4*)w = *(float4*)&sW1[kk][j0];
      #pragma unroll
      for (int j=0;j<4;j++) a0[j] = fmaf(a, w[j], a0[j]);
    }
    float4 o;
    o.x=fmaxf(a0[0],0.f); o.y=fmaxf(a0[1],0.f); o.z=fmaxf(a0[2],0.f); o.w=fmaxf(a0[3],0.f);
    *(float4*)&sm1[tok][j0] = o;
  }
  __syncthreads();
  {
    int tok = tid>>3, j0 = (tid&7)*4;
    float a0[4];
    #pragma unroll
    for (int j=0;j<4;j++) a0[j] = b2[j0+j];
    #pragma unroll
    for (int kk=0;kk<32;kk++){
      float a = sm1[tok][kk];
      float w[4]; *(float4*)w = *(float4*)&sW2[kk][j0];
      #pragma unroll
      for (int j=0;j<4;j++) a0[j] = fmaf(a, w[j], a0[j]);
    }
    float4 o;
    o.x=fmaxf(a0[0],0.f); o.y=fmaxf(a0[1],0.f); o.z=fmaxf(a0[2],0.f); o.w=fmaxf(a0[3],0.f);
    *(float4*)&sm2[tok][j0] = o;
  }
  __syncthreads();
  if (tid < 32){
    float t = 0.f;
    #pragma unroll
    for (int tok=0;tok<32;tok++) t += sm2[tok][tid];
    atomicAdd(&macc[b*32 + tid], t);
  }
}

// ----- K9: angle[b] = mean_m @ Wo + bo -----
__global__ void k_final(const float* __restrict__ macc, const float* __restrict__ Wo,
                        const float* __restrict__ bo, float* __restrict__ out){
  int tid = threadIdx.x;
  if (tid < 4){
    float acc = bo[0];
    #pragma unroll
    for (int j=0;j<32;j++) acc = fmaf(macc[tid*32+j]*(1.f/4096.f), Wo[j], acc);
    out[tid] = acc;
  }
}

// ---------------------------------------------------------------------------
extern "C" void kernel_launch(void* const* d_in, const int* in_sizes, int n_in,
                              void* d_out, int out_size, void* d_ws, size_t ws_size,
                              hipStream_t stream){
  const float* x      = (const float*)d_in[0];
  const float* Wfc    = (const float*)d_in[1];
  const float* bfc    = (const float*)d_in[2];
  const float* W_in   = (const float*)d_in[3];
  const float* conv_w = (const float*)d_in[4];
  const float* conv_b = (const float*)d_in[5];
  const float* dt_bias= (const float*)d_in[6];
  const float* A_log  = (const float*)d_in[7];
  const float* Dparam = (const float*)d_in[8];
  const float* norm_w = (const float*)d_in[9];
  const float* W_out  = (const float*)d_in[10];
  const float* W1     = (const float*)d_in[11];
  const float* b1     = (const float*)d_in[12];
  const float* W2     = (const float*)d_in[13];
  const float* b2     = (const float*)d_in[14];
  const float* Wo     = (const float*)d_in[15];
  const float* bo     = (const float*)d_in[16];
  float* ws  = (float*)d_ws;
  float* out = (float*)d_out;

  float* h    = ws + OFF_H;
  float* zb   = ws + OFF_Z;
  float* xbc  = ws + OFF_XBC;
  float* Tb   = ws + OFF_T;
  float* xsb  = ws + OFF_XS;
  float* Bmb  = ws + OFF_BM;
  float* Cmb  = ws + OFF_CM;
  float* dtb  = ws + OFF_DT;
  float* lacb = ws + OFF_LAC;
  float* Spb  = ws + OFF_SP;
  float* yb   = ws + OFF_Y;
  float* macc = ws + OFF_MACC;
  float* h2   = ws + OFF_H2;

  hipMemsetAsync((void*)macc, 0, 128*sizeof(float), stream);

  k_fc<<<dim3(BL), dim3(192), 0, stream>>>(x, Wfc, bfc, h);
  k_gemm<192,904,1><<<dim3(128,8), dim3(256), 0, stream>>>(
      h, W_in, nullptr, zb, xbc, dtb, dt_bias, A_log);
  k_conv<<<dim3(BL*512/256), dim3(256), 0, stream>>>(xbc, conv_w, conv_b, xsb, Bmb, Cmb);
  k_phase1<<<dim3(BH*NC), dim3(256), 0, stream>>>(dtb, Bmb, xsb, A_log, Tb, lacb);
  k_phase2<<<dim3(BH), dim3(1024), 0, stream>>>(Tb, lacb, Spb);
  k_phase3<<<dim3(BH*NC), dim3(256), 0, stream>>>(dtb, lacb, Bmb, Cmb, xsb, Spb, Dparam, yb);
  k_gate<<<dim3(BL), dim3(384), 0, stream>>>(zb, norm_w, yb);
  k_gemm<384,192,0><<<dim3(128,2), dim3(256), 0, stream>>>(
      yb, W_out, h2, nullptr, nullptr, nullptr, nullptr, nullptr);
  k_mlp<<<dim3(BL/32), dim3(256), 0, stream>>>(h2, W1, b1, W2, b2, macc);
  k_final<<<dim3(1), dim3(64), 0, stream>>>(macc, Wo, bo, out);
}

// Round 2
// 412.794 us; speedup vs baseline: 1.4519x; 1.4519x over previous
//
#include <hip/hip_runtime.h>
#include <math.h>

// ---------------------------------------------------------------------------
// MambaAnglePredictor: fc -> in_proj -> conv+silu -> chunked SSM scan (SSD)
//   -> gate+RMSNorm -> out_proj -> MLP -> mean -> angle
// Round 2: phase3 rewritten conflict-free (transposed LDS, stride 68),
//          LDS 75->53KB (3 blocks/CU), single accumulator; phase2 8x blocks.
// ---------------------------------------------------------------------------

#define BDIM 4
#define LDIM 4096
#define BL (BDIM*LDIM)      // 16384 tokens
#define DM 192
#define DIP 904
#define DI 384
#define DS 64
#define NH 8
#define HD 48
#define CONVD 512
#define QC 64               // chunk length
#define NC (LDIM/QC)        // 64 chunks
#define BH (BDIM*NH)        // 32

// workspace offsets (floats). total = 39,059,584 floats = 156.2 MB
#define OFF_H    0u          // 16384*192      (reused as h2 after scan)
#define OFF_Z    3145728u    // 16384*384
#define OFF_XBC  9437184u    // 16384*512      (reused as T after conv)
#define OFF_T    OFF_XBC     // 2048*3072
#define OFF_XS   17825792u   // 32*4096*48
#define OFF_BM   24117248u   // 16384*64
#define OFF_CM   25165824u   // 16384*64
#define OFF_DT   26214400u   // 32*4096
#define OFF_LAC  26345472u   // 2048*64
#define OFF_SP   26476544u   // 2048*3072
#define OFF_Y    32768000u   // 16384*384
#define OFF_MACC 39059456u   // 4*32
#define OFF_H2   OFF_H

__device__ __forceinline__ float sigmoidf_(float x){ return 1.0f/(1.0f+__expf(-x)); }

// --------------------------- K1: h = x@Wfc + bfc ---------------------------
__global__ void k_fc(const float* __restrict__ x, const float* __restrict__ Wfc,
                     const float* __restrict__ bfc, float* __restrict__ h){
  int bl = blockIdx.x; int d = threadIdx.x;
  float4 xv = *(const float4*)(x + bl*4);
  float acc = bfc[d];
  acc = fmaf(xv.x, Wfc[d], acc);
  acc = fmaf(xv.y, Wfc[192+d], acc);
  acc = fmaf(xv.z, Wfc[384+d], acc);
  acc = fmaf(xv.w, Wfc[576+d], acc);
  h[(size_t)bl*192 + d] = acc;
}

// ----------------- generic 128x128-tile fp32 GEMM, 8x8/thread --------------
// MODE 0: plain store to out (stride ND). MODE 1: in_proj split epilogue.
template<int KD, int ND, int MODE>
__global__ __launch_bounds__(256) void k_gemm(
    const float* __restrict__ A, const float* __restrict__ Bw,
    float* __restrict__ out,
    float* __restrict__ zbuf, float* __restrict__ xbc, float* __restrict__ dtbuf,
    const float* __restrict__ dt_bias, const float* __restrict__ A_log){
  __shared__ __align__(16) float sA[16][132];   // [kk][m]
  __shared__ __align__(16) float sB[16][132];   // [kk][n]
  int tid = threadIdx.x;
  int m0 = blockIdx.x*128, n0 = blockIdx.y*128;
  int ty = tid>>4, tx = tid&15;
  float acc[8][8];
  #pragma unroll
  for (int i=0;i<8;i++)
    #pragma unroll
    for (int j=0;j<8;j++) acc[i][j]=0.f;

  for (int k0=0;k0<KD;k0+=16){
    {
      int r = tid>>2, kc = (tid&3)*4;
      #pragma unroll
      for (int p=0;p<2;p++){
        int row = r + p*64;
        float4 v = *(const float4*)(A + (size_t)(m0+row)*KD + k0 + kc);
        sA[kc+0][row]=v.x; sA[kc+1][row]=v.y; sA[kc+2][row]=v.z; sA[kc+3][row]=v.w;
      }
      int kk = tid>>4, nc0 = (tid&15)*4;
      #pragma unroll
      for (int p=0;p<2;p++){
        int nc = nc0 + p*64;
        float4 v;
        if (n0+nc < ND) v = *(const float4*)(Bw + (size_t)(k0+kk)*ND + n0 + nc);
        else v = make_float4(0.f,0.f,0.f,0.f);
        *(float4*)&sB[kk][nc] = v;
      }
    }
    __syncthreads();
    #pragma unroll
    for (int kk=0;kk<16;kk++){
      float ar[8], br[8];
      *(float4*)&ar[0] = *(float4*)&sA[kk][ty*4];
      *(float4*)&ar[4] = *(float4*)&sA[kk][64+ty*4];
      *(float4*)&br[0] = *(float4*)&sB[kk][tx*4];
      *(float4*)&br[4] = *(float4*)&sB[kk][64+tx*4];
      #pragma unroll
      for (int i=0;i<8;i++)
        #pragma unroll
        for (int j=0;j<8;j++) acc[i][j] = fmaf(ar[i], br[j], acc[i][j]);
    }
    __syncthreads();
  }
  #pragma unroll
  for (int i=0;i<8;i++){
    int m = m0 + ((i<4)? ty*4+i : 64+ty*4+(i-4));
    #pragma unroll
    for (int j=0;j<8;j++){
      int n = n0 + ((j<4)? tx*4+j : 64+tx*4+(j-4));
      float v = acc[i][j];
      if (MODE==0){
        if (n < ND) out[(size_t)m*ND + n] = v;
      } else {
        if (n < 384){
          zbuf[(size_t)m*384 + n] = v;
        } else if (n < 896){
          xbc[(size_t)m*512 + (n-384)] = v;
        } else if (n < 904){
          int hh = n - 896;
          float xx = v + dt_bias[hh];
          float dtv = (xx > 20.f) ? xx : log1pf(__expf(xx));
          int b = m >> 12, l = m & 4095;
          dtbuf[(size_t)(b*8+hh)*4096 + l] = dtv;
        }
      }
    }
  }
}

// ------------------- K3: depthwise causal conv(4) + silu -------------------
__global__ void k_conv(const float* __restrict__ xbc, const float* __restrict__ conv_w,
                       const float* __restrict__ conv_b, float* __restrict__ xs,
                       float* __restrict__ Bm, float* __restrict__ Cm){
  int idx = blockIdx.x*256 + threadIdx.x;
  int bl = idx >> 9, c = idx & 511;
  int l = bl & 4095, b = bl >> 12;
  float acc = conv_b[c];
  #pragma unroll
  for (int k=0;k<4;k++){
    int ll = l - 3 + k;
    if (ll >= 0) acc = fmaf(conv_w[k*512+c], xbc[(size_t)(bl-3+k)*512 + c], acc);
  }
  float v = acc * sigmoidf_(acc);
  if (c < 384){
    int hh = c / 48, p = c - hh*48;
    xs[(size_t)((b*8+hh)*4096 + l)*48 + p] = v;
  } else if (c < 448){
    Bm[(size_t)bl*64 + (c-384)] = v;
  } else {
    Cm[(size_t)bl*64 + (c-448)] = v;
  }
}

// ----- K4 phase1: per-chunk cumlog(dA), chunk state T_k = sum w_s B_s x_s^T -----
__global__ __launch_bounds__(256) void k_phase1(
    const float* __restrict__ dtbuf, const float* __restrict__ Bm,
    const float* __restrict__ xs, const float* __restrict__ A_log,
    float* __restrict__ T, float* __restrict__ lac){
  __shared__ float sdt[64], sla[64], sw[64];
  __shared__ __align__(16) float sBW[64][64];
  __shared__ __align__(16) float sX[64][48];
  int tid = threadIdx.x, blk = blockIdx.x;
  int bh = blk >> 6, k = blk & 63;
  int b = bh >> 3, hh = bh & 7;
  int t0 = k*64;
  if (tid < 64) sdt[tid] = dtbuf[(size_t)bh*4096 + t0 + tid];
  __syncthreads();
  if (tid == 0){
    float eA = __expf(A_log[hh]);
    float cum = 0.f;
    for (int i=0;i<64;i++){ cum -= sdt[i]*eA; sla[i] = cum; }
  }
  __syncthreads();
  if (tid < 64){
    sw[tid] = __expf(sla[63]-sla[tid])*sdt[tid];
    lac[(size_t)blk*64 + tid] = sla[tid];
  }
  __syncthreads();
  {
    int s = tid>>2, n0 = (tid&3)*16;
    float wsc = sw[s];
    const float* src = Bm + (size_t)(b*4096 + t0 + s)*64 + n0;
    #pragma unroll
    for (int q=0;q<4;q++){
      float4 v = *(const float4*)(src + q*4);
      v.x*=wsc; v.y*=wsc; v.z*=wsc; v.w*=wsc;
      *(float4*)&sBW[s][n0+q*4] = v;
    }
    int p0 = (tid&3)*12;
    const float* xsrc = xs + (size_t)(bh*4096 + t0 + s)*48 + p0;
    #pragma unroll
    for (int q=0;q<3;q++) *(float4*)&sX[s][p0+q*4] = *(const float4*)(xsrc + q*4);
  }
  __syncthreads();
  if (tid < 192){
    int n0 = (tid/12)*4, p0 = (tid%12)*4;
    float acc[4][4];
    #pragma unroll
    for (int i=0;i<4;i++)
      #pragma unroll
      for (int j=0;j<4;j++) acc[i][j]=0.f;
    for (int s=0;s<64;s++){
      float bw[4], xv[4];
      *(float4*)bw = *(float4*)&sBW[s][n0];
      *(float4*)xv = *(float4*)&sX[s][p0];
      #pragma unroll
      for (int i=0;i<4;i++)
        #pragma unroll
        for (int j=0;j<4;j++) acc[i][j] = fmaf(bw[i], xv[j], acc[i][j]);
    }
    float* dst = T + (size_t)blk*3072;
    #pragma unroll
    for (int i=0;i<4;i++){
      float4 o; o.x=acc[i][0]; o.y=acc[i][1]; o.z=acc[i][2]; o.w=acc[i][3];
      *(float4*)(dst + (n0+i)*48 + p0) = o;
    }
  }
}

// ----- K5 phase2: sequential chunk-carry; stores S_prev per chunk -----
// grid (BH, 8), 384 threads: each thread owns 1 of 3072 state elements.
__global__ __launch_bounds__(384) void k_phase2(
    const float* __restrict__ T, const float* __restrict__ lac, float* __restrict__ Sp){
  __shared__ float ssc[64];
  int tid = threadIdx.x, bh = blockIdx.x, sl = blockIdx.y;
  if (tid < 64) ssc[tid] = __expf(lac[(size_t)(bh*64+tid)*64 + 63]);
  __syncthreads();
  size_t base = (size_t)bh*64*3072 + sl*384 + tid;
  float s = 0.f;
  float nv = T[base];
  for (int k=0;k<64;k++){
    float c = nv;
    if (k<63) nv = T[base + (size_t)(k+1)*3072];
    Sp[base + (size_t)k*3072] = s;
    s = fmaf(ssc[k], s, c);
  }
}

// ----- K6 phase3: Y = (L o C B^T) X + diag(exp(la)) C S_prev + D*x -----
// Conflict-free LDS: sBt/sCt transposed [n][token], stride 68 (68%32=4).
// Buffer reuse: sSG holds Sp[n][p] then GM^T[s][i]; sBt holds B^T then X[s][p].
// LDS = 3*64*68*4 + 512 = 52.7 KB -> 3 blocks/CU.
__global__ __launch_bounds__(256, 3) void k_phase3(
    const float* __restrict__ dtbuf, const float* __restrict__ lac,
    const float* __restrict__ Bm, const float* __restrict__ Cm,
    const float* __restrict__ xs, const float* __restrict__ Sp,
    const float* __restrict__ Dparam, float* __restrict__ y){
  __shared__ __align__(16) float sBt[64][68];  // B^T [n][s] -> X [s][p]
  __shared__ __align__(16) float sCt[64][68];  // C^T [n][i]
  __shared__ __align__(16) float sSG[64][68];  // Sp [n][p] -> GM^T [s][i]
  __shared__ float sdt[64], sla[64];
  int tid = threadIdx.x, blk = blockIdx.x;
  int bh = blk>>6, k = blk&63, b = bh>>3, hh = bh&7, t0 = k*64;

  // ---- stage A: loads ----
  int rs = tid>>2, c0 = (tid&3)*12;           // X/Sp copy mapping
  float4 xpre0, xpre1, xpre2;                 // X prefetch (stored to LDS in stage C)
  {
    const float* xsrc = xs + (size_t)(bh*4096+t0+rs)*48 + c0;
    xpre0 = *(const float4*)(xsrc);
    xpre1 = *(const float4*)(xsrc+4);
    xpre2 = *(const float4*)(xsrc+8);
  }
  if (tid < 64){
    sdt[tid] = dtbuf[(size_t)bh*4096 + t0 + tid];
    sla[tid] = lac[(size_t)blk*64 + tid];
  }
  {
    const float* ssrc = Sp + (size_t)blk*3072 + rs*48 + c0;
    *(float4*)&sSG[rs][c0]   = *(const float4*)(ssrc);
    *(float4*)&sSG[rs][c0+4] = *(const float4*)(ssrc+4);
    *(float4*)&sSG[rs][c0+8] = *(const float4*)(ssrc+8);
  }
  {
    int s = tid>>2, n0 = (tid&3)*16;
    const float* bsrc = Bm + (size_t)(b*4096+t0+s)*64 + n0;
    const float* csrc = Cm + (size_t)(b*4096+t0+s)*64 + n0;
    #pragma unroll
    for (int q=0;q<4;q++){
      float4 bv = *(const float4*)(bsrc + q*4);
      float4 cv = *(const float4*)(csrc + q*4);
      sBt[n0+q*4+0][s]=bv.x; sBt[n0+q*4+1][s]=bv.y; sBt[n0+q*4+2][s]=bv.z; sBt[n0+q*4+3][s]=bv.w;
      sCt[n0+q*4+0][s]=cv.x; sCt[n0+q*4+1][s]=cv.y; sCt[n0+q*4+2][s]=cv.z; sCt[n0+q*4+3][s]=cv.w;
    }
  }
  __syncthreads();

  // ---- stage B: ia = C @ Sp (192 threads), GM = tril(C B^T) (256 threads) ----
  int i0p = (tid/12)*4, p0 = (tid%12)*4;      // (i,p) mapping, tid<192
  float acc[4][4];
  #pragma unroll
  for (int i=0;i<4;i++)
    #pragma unroll
    for (int j=0;j<4;j++) acc[i][j]=0.f;
  if (tid < 192){
    #pragma unroll 4
    for (int n=0;n<64;n++){
      float cv[4], sp[4];
      *(float4*)cv = *(float4*)&sCt[n][i0p];
      *(float4*)sp = *(float4*)&sSG[n][p0];
      #pragma unroll
      for (int ii=0;ii<4;ii++)
        #pragma unroll
        for (int j=0;j<4;j++) acc[ii][j] = fmaf(cv[ii], sp[j], acc[ii][j]);
    }
  }
  int ig = (tid>>4)*4, sg = (tid&15)*4;       // (i,s) mapping, all 256
  float gm[4][4];
  #pragma unroll
  for (int i=0;i<4;i++)
    #pragma unroll
    for (int j=0;j<4;j++) gm[i][j]=0.f;
  if (sg <= ig+3){
    #pragma unroll 4
    for (int n=0;n<64;n++){
      float cv[4], bv[4];
      *(float4*)cv = *(float4*)&sCt[n][ig];
      *(float4*)bv = *(float4*)&sBt[n][sg];
      #pragma unroll
      for (int ii=0;ii<4;ii++)
        #pragma unroll
        for (int ss=0;ss<4;ss++) gm[ii][ss] = fmaf(cv[ii], bv[ss], gm[ii][ss]);
    }
    #pragma unroll
    for (int ii=0;ii<4;ii++)
      #pragma unroll
      for (int ss=0;ss<4;ss++){
        int i = ig+ii, s = sg+ss;
        gm[ii][ss] = (s<=i) ? gm[ii][ss]*__expf(sla[i]-sla[s])*sdt[s] : 0.f;
      }
  }
  __syncthreads();

  // ---- stage C: GM -> sSG[s][i]; X -> sBt[s][p]; scale acc by exp(la_i) ----
  #pragma unroll
  for (int ss=0;ss<4;ss++){
    float4 o; o.x=gm[0][ss]; o.y=gm[1][ss]; o.z=gm[2][ss]; o.w=gm[3][ss];
    *(float4*)&sSG[sg+ss][ig] = o;
  }
  *(float4*)&sBt[rs][c0]   = xpre0;
  *(float4*)&sBt[rs][c0+4] = xpre1;
  *(float4*)&sBt[rs][c0+8] = xpre2;
  if (tid < 192){
    #pragma unroll
    for (int ii=0;ii<4;ii++){
      float ci = __expf(sla[i0p+ii]);
      #pragma unroll
      for (int j=0;j<4;j++) acc[ii][j] *= ci;
    }
  }
  __syncthreads();

  // ---- stage D: acc += sum_{s<=i} GM[i][s] X[s][p]; + D*x; store ----
  if (tid < 192){
    for (int s0=0; s0<=i0p; s0+=4){
      #pragma unroll
      for (int q=0;q<4;q++){
        float gv[4], xv[4];
        *(float4*)gv = *(float4*)&sSG[s0+q][i0p];
        *(float4*)xv = *(float4*)&sBt[s0+q][p0];
        #pragma unroll
        for (int ii=0;ii<4;ii++)
          #pragma unroll
          for (int j=0;j<4;j++) acc[ii][j] = fmaf(gv[ii], xv[j], acc[ii][j]);
      }
    }
    float Dh = Dparam[hh];
    #pragma unroll
    for (int ii=0;ii<4;ii++){
      int i = i0p+ii;
      float4 xd = *(float4*)&sBt[i][p0];
      float4 o;
      o.x = acc[ii][0] + Dh*xd.x;
      o.y = acc[ii][1] + Dh*xd.y;
      o.z = acc[ii][2] + Dh*xd.z;
      o.w = acc[ii][3] + Dh*xd.w;
      *(float4*)(y + (size_t)(b*4096+t0+i)*384 + hh*48 + p0) = o;
    }
  }
}

// ----- K7a: v = y*silu(z); RMSNorm*norm_w, in-place into y -----
__global__ __launch_bounds__(384) void k_gate(
    const float* __restrict__ zbuf, const float* __restrict__ norm_w, float* __restrict__ y){
  __shared__ float sred[6];
  __shared__ float srms;
  int bl = blockIdx.x, tid = threadIdx.x;
  float yv = y[(size_t)bl*384 + tid];
  float zv = zbuf[(size_t)bl*384 + tid];
  float g = yv * (zv * sigmoidf_(zv));
  float ss = g*g;
  #pragma unroll
  for (int off=32; off>0; off>>=1) ss += __shfl_xor(ss, off);
  if ((tid&63)==0) sred[tid>>6] = ss;
  __syncthreads();
  if (tid==0){
    float t=0.f;
    #pragma unroll
    for (int i=0;i<6;i++) t += sred[i];
    srms = rsqrtf(t*(1.f/384.f) + 1e-5f);
  }
  __syncthreads();
  y[(size_t)bl*384 + tid] = g * srms * norm_w[tid];
}

// ----- K8: MLP (192->32 relu, 32->32 relu) + partial mean accumulation -----
__global__ __launch_bounds__(256) void k_mlp(
    const float* __restrict__ h2, const float* __restrict__ W1, const float* __restrict__ b1,
    const float* __restrict__ W2, const float* __restrict__ b2, float* __restrict__ macc){
  __shared__ __align__(16) float sh2[32][192];
  __shared__ __align__(16) float sW1[192][32];
  __shared__ __align__(16) float sm1[32][32];
  __shared__ __align__(16) float sW2[32][32];
  __shared__ __align__(16) float sm2[32][32];
  int tid = threadIdx.x;
  int tok0 = blockIdx.x*32;
  int b = tok0 >> 12;
  #pragma unroll
  for (int r=0;r<6;r++){
    int e4 = tid + r*256;
    int row = e4/48, c4 = (e4%48)*4;
    *(float4*)&sh2[row][c4] = *(const float4*)(h2 + (size_t)(tok0+row)*192 + c4);
  }
  #pragma unroll
  for (int r=0;r<6;r++){
    int e4 = tid + r*256;
    int row = e4>>3, c4 = (e4&7)*4;
    *(float4*)&sW1[row][c4] = *(const float4*)(W1 + row*32 + c4);
  }
  {
    int row = tid>>3, c4 = (tid&7)*4;
    *(float4*)&sW2[row][c4] = *(const float4*)(W2 + row*32 + c4);
  }
  __syncthreads();
  {
    int tok = tid>>3, j0 = (tid&7)*4;
    float a0[4];
    #pragma unroll
    for (int j=0;j<4;j++) a0[j] = b1[j0+j];
    for (int kk=0;kk<192;kk++){
      float a = sh2[tok][kk];
      float w[4]; *(float4*)w = *(float4*)&sW1[kk][j0];
      #pragma unroll
      for (int j=0;j<4;j++) a0[j] = fmaf(a, w[j], a0[j]);
    }
    float4 o;
    o.x=fmaxf(a0[0],0.f); o.y=fmaxf(a0[1],0.f); o.z=fmaxf(a0[2],0.f); o.w=fmaxf(a0[3],0.f);
    *(float4*)&sm1[tok][j0] = o;
  }
  __syncthreads();
  {
    int tok = tid>>3, j0 = (tid&7)*4;
    float a0[4];
    #pragma unroll
    for (int j=0;j<4;j++) a0[j] = b2[j0+j];
    #pragma unroll
    for (int kk=0;kk<32;kk++){
      float a = sm1[tok][kk];
      float w[4]; *(float4*)w = *(float4*)&sW2[kk][j0];
      #pragma unroll
      for (int j=0;j<4;j++) a0[j] = fmaf(a, w[j], a0[j]);
    }
    float4 o;
    o.x=fmaxf(a0[0],0.f); o.y=fmaxf(a0[1],0.f); o.z=fmaxf(a0[2],0.f); o.w=fmaxf(a0[3],0.f);
    *(float4*)&sm2[tok][j0] = o;
  }
  __syncthreads();
  if (tid < 32){
    float t = 0.f;
    #pragma unroll
    for (int tok=0;tok<32;tok++) t += sm2[tok][tid];
    atomicAdd(&macc[b*32 + tid], t);
  }
}

// ----- K9: angle[b] = mean_m @ Wo + bo -----
__global__ void k_final(const float* __restrict__ macc, const float* __restrict__ Wo,
                        const float* __restrict__ bo, float* __restrict__ out){
  int tid = threadIdx.x;
  if (tid < 4){
    float acc = bo[0];
    #pragma unroll
    for (int j=0;j<32;j++) acc = fmaf(macc[tid*32+j]*(1.f/4096.f), Wo[j], acc);
    out[tid] = acc;
  }
}

// ---------------------------------------------------------------------------
extern "C" void kernel_launch(void* const* d_in, const int* in_sizes, int n_in,
                              void* d_out, int out_size, void* d_ws, size_t ws_size,
                              hipStream_t stream){
  const float* x      = (const float*)d_in[0];
  const float* Wfc    = (const float*)d_in[1];
  const float* bfc    = (const float*)d_in[2];
  const float* W_in   = (const float*)d_in[3];
  const float* conv_w = (const float*)d_in[4];
  const float* conv_b = (const float*)d_in[5];
  const float* dt_bias= (const float*)d_in[6];
  const float* A_log  = (const float*)d_in[7];
  const float* Dparam = (const float*)d_in[8];
  const float* norm_w = (const float*)d_in[9];
  const float* W_out  = (const float*)d_in[10];
  const float* W1     = (const float*)d_in[11];
  const float* b1     = (const float*)d_in[12];
  const float* W2     = (const float*)d_in[13];
  const float* b2     = (const float*)d_in[14];
  const float* Wo     = (const float*)d_in[15];
  const float* bo     = (const float*)d_in[16];
  float* ws  = (float*)d_ws;
  float* out = (float*)d_out;

  float* h    = ws + OFF_H;
  float* zb   = ws + OFF_Z;
  float* xbc  = ws + OFF_XBC;
  float* Tb   = ws + OFF_T;
  float* xsb  = ws + OFF_XS;
  float* Bmb  = ws + OFF_BM;
  float* Cmb  = ws + OFF_CM;
  float* dtb  = ws + OFF_DT;
  float* lacb = ws + OFF_LAC;
  float* Spb  = ws + OFF_SP;
  float* yb   = ws + OFF_Y;
  float* macc = ws + OFF_MACC;
  float* h2   = ws + OFF_H2;

  hipMemsetAsync((void*)macc, 0, 128*sizeof(float), stream);

  k_fc<<<dim3(BL), dim3(192), 0, stream>>>(x, Wfc, bfc, h);
  k_gemm<192,904,1><<<dim3(128,8), dim3(256), 0, stream>>>(
      h, W_in, nullptr, zb, xbc, dtb, dt_bias, A_log);
  k_conv<<<dim3(BL*512/256), dim3(256), 0, stream>>>(xbc, conv_w, conv_b, xsb, Bmb, Cmb);
  k_phase1<<<dim3(BH*NC), dim3(256), 0, stream>>>(dtb, Bmb, xsb, A_log, Tb, lacb);
  k_phase2<<<dim3(BH,8), dim3(384), 0, stream>>>(Tb, lacb, Spb);
  k_phase3<<<dim3(BH*NC), dim3(256), 0, stream>>>(dtb, lacb, Bmb, Cmb, xsb, Spb, Dparam, yb);
  k_gate<<<dim3(BL), dim3(384), 0, stream>>>(zb, norm_w, yb);
  k_gemm<384,192,0><<<dim3(128,2), dim3(256), 0, stream>>>(
      yb, W_out, h2, nullptr, nullptr, nullptr, nullptr, nullptr);
  k_mlp<<<dim3(BL/32), dim3(256), 0, stream>>>(h2, W1, b1, W2, b2, macc);
  k_final<<<dim3(1), dim3(64), 0, stream>>>(macc, Wo, bo, out);
}

// Round 3
// 324.869 us; speedup vs baseline: 1.8448x; 1.2706x over previous
//
#include <hip/hip_runtime.h>
#include <math.h>

// ---------------------------------------------------------------------------
// MambaAnglePredictor: fc -> in_proj -> conv+silu -> chunked SSM scan (SSD)
//   -> gate+RMSNorm -> out_proj -> MLP -> mean -> angle
// Round 3: in_proj/out_proj GEMMs on MFMA (bf16 3-term split, fp32-accurate).
// ---------------------------------------------------------------------------

#define BDIM 4
#define LDIM 4096
#define BL (BDIM*LDIM)      // 16384 tokens
#define DM 192
#define DI 384
#define DS 64
#define NH 8
#define HD 48
#define QC 64               // chunk length
#define NC (LDIM/QC)        // 64 chunks
#define BH (BDIM*NH)        // 32

// workspace offsets (floats). total = 39,059,584 floats = 156.2 MB (unchanged)
#define OFF_H    0u          // h_hi/h_lo bf16 (3,145,728 fl total); later h2 fp32
#define OFF_Z    3145728u    // z fp32 16384*384
#define OFF_XBC  9437184u    // xbc fp32 -> T -> y_hi/y_lo bf16
#define OFF_T    OFF_XBC
#define OFF_XS   17825792u   // 32*4096*48
#define OFF_BM   24117248u   // 16384*64
#define OFF_CM   25165824u   // 16384*64
#define OFF_DT   26214400u   // 32*4096
#define OFF_LAC  26345472u   // 2048*64
#define OFF_SP   26476544u   // Wt_in early / Sp mid / Wt_out late
#define OFF_Y    32768000u   // 16384*384 fp32
#define OFF_MACC 39059456u   // 4*32

typedef unsigned short ushort_t;
typedef __attribute__((ext_vector_type(8))) short bf16x8;
typedef __attribute__((ext_vector_type(4))) float f32x4;

__device__ __forceinline__ float sigmoidf_(float x){ return 1.0f/(1.0f+__expf(-x)); }
__device__ __forceinline__ ushort_t f2bf(float x){
  unsigned int u = __float_as_uint(x);
  u += 0x7fffu + ((u>>16)&1u);
  return (ushort_t)(u>>16);
}
__device__ __forceinline__ float bf2f(ushort_t h){
  return __uint_as_float(((unsigned int)h)<<16);
}

// ------------------ K1: h = x@Wfc + bfc, emitted as bf16 hi/lo --------------
__global__ void k_fc(const float* __restrict__ x, const float* __restrict__ Wfc,
                     const float* __restrict__ bfc,
                     ushort_t* __restrict__ hhi, ushort_t* __restrict__ hlo){
  int bl = blockIdx.x; int d = threadIdx.x;
  float4 xv = *(const float4*)(x + bl*4);
  float acc = bfc[d];
  acc = fmaf(xv.x, Wfc[d], acc);
  acc = fmaf(xv.y, Wfc[192+d], acc);
  acc = fmaf(xv.z, Wfc[384+d], acc);
  acc = fmaf(xv.w, Wfc[576+d], acc);
  ushort_t hi = f2bf(acc);
  size_t idx = (size_t)bl*192 + d;
  hhi[idx] = hi;
  hlo[idx] = f2bf(acc - bf2f(hi));
}

// ------- weight pre-transform: W(KxN fp32) -> hi/lo bf16 [K/32][Npad][32] ----
template<int K, int N, int Npad>
__global__ void k_wt(const float* __restrict__ W,
                     ushort_t* __restrict__ Wh, ushort_t* __restrict__ Wl){
  int kt = blockIdx.x;
  int n = blockIdx.y*256 + threadIdx.x;
  if (n >= Npad) return;
  for (int k=0;k<32;k++){
    float v = (n < N) ? W[(size_t)(kt*32+k)*N + n] : 0.f;
    ushort_t hi = f2bf(v);
    size_t o = ((size_t)kt*Npad + n)*32 + k;
    Wh[o] = hi;
    Wl[o] = f2bf(v - bf2f(hi));
  }
}

// ------------- MFMA split-bf16 GEMM: 128 x BN tile, 4 waves -----------------
// A: M x K bf16 hi/lo row-major. B: transformed [K/32][Npad][32] hi/lo.
// MODE 0: out[m*N+n] fp32. MODE 1: in_proj epilogue (z / xbc / softplus dt).
template<int K, int N, int Npad, int BN, int MODE>
__global__ __launch_bounds__(256) void k_mgemm(
    const ushort_t* __restrict__ Ah, const ushort_t* __restrict__ Al,
    const ushort_t* __restrict__ Bh, const ushort_t* __restrict__ Bl,
    float* __restrict__ out, float* __restrict__ zbuf, float* __restrict__ xbcb,
    float* __restrict__ dtbuf, const float* __restrict__ dt_bias){
  __shared__ __align__(16) short sAh[128*40];
  __shared__ __align__(16) short sAl[128*40];
  __shared__ __align__(16) short sBh[BN*40];
  __shared__ __align__(16) short sBl[BN*40];
  const int NF = BN/32;                 // n-frags per wave
  int tid = threadIdx.x;
  int m0 = blockIdx.x*128, n0 = blockIdx.y*BN;
  int w = tid>>6, lane = tid&63;
  int wm = (w>>1)*64, wn = (w&1)*(BN/2);
  int l15 = lane&15, quad = lane>>4;

  f32x4 acc[4][NF];
  #pragma unroll
  for (int i=0;i<4;i++)
    #pragma unroll
    for (int j=0;j<NF;j++) acc[i][j] = (f32x4)(0.f);

  for (int k0=0;k0<K;k0+=32){
    // stage A (128 rows x 32 bf16, hi+lo), padded stride 40
    #pragma unroll
    for (int p=0;p<2;p++){
      int seg = tid + p*256;
      int row = seg>>2, off = (seg&3)*8;
      size_t g = (size_t)(m0+row)*K + k0 + off;
      *(uint4*)&sAh[row*40+off] = *(const uint4*)(Ah + g);
      *(uint4*)&sAl[row*40+off] = *(const uint4*)(Al + g);
    }
    // stage B (BN rows x 32 bf16, hi+lo) from transformed layout (contiguous)
    #pragma unroll
    for (int p=0;p<2;p++){
      int seg = tid + p*256;
      if (seg < BN*4){
        int row = seg>>2, off = (seg&3)*8;
        size_t g = ((size_t)(k0>>5)*Npad + n0 + row)*32 + off;
        *(uint4*)&sBh[row*40+off] = *(const uint4*)(Bh + g);
        *(uint4*)&sBl[row*40+off] = *(const uint4*)(Bl + g);
      }
    }
    __syncthreads();
    bf16x8 fAh[4], fAl[4], fBh[NF], fBl[NF];
    #pragma unroll
    for (int mi=0;mi<4;mi++){
      int r = wm + mi*16 + l15;
      fAh[mi] = *(bf16x8*)&sAh[r*40 + quad*8];
      fAl[mi] = *(bf16x8*)&sAl[r*40 + quad*8];
    }
    #pragma unroll
    for (int ni=0;ni<NF;ni++){
      int r = wn + ni*16 + l15;
      fBh[ni] = *(bf16x8*)&sBh[r*40 + quad*8];
      fBl[ni] = *(bf16x8*)&sBl[r*40 + quad*8];
    }
    #pragma unroll
    for (int mi=0;mi<4;mi++)
      #pragma unroll
      for (int ni=0;ni<NF;ni++){
        acc[mi][ni] = __builtin_amdgcn_mfma_f32_16x16x32_bf16(fAh[mi], fBh[ni], acc[mi][ni], 0,0,0);
        acc[mi][ni] = __builtin_amdgcn_mfma_f32_16x16x32_bf16(fAh[mi], fBl[ni], acc[mi][ni], 0,0,0);
        acc[mi][ni] = __builtin_amdgcn_mfma_f32_16x16x32_bf16(fAl[mi], fBh[ni], acc[mi][ni], 0,0,0);
      }
    __syncthreads();
  }
  // epilogue: C/D layout col = lane&15, row = quad*4 + reg
  #pragma unroll
  for (int mi=0;mi<4;mi++)
    #pragma unroll
    for (int ni=0;ni<NF;ni++)
      #pragma unroll
      for (int r=0;r<4;r++){
        int m = m0 + wm + mi*16 + quad*4 + r;
        int n = n0 + wn + ni*16 + l15;
        float v = acc[mi][ni][r];
        if (MODE==0){
          out[(size_t)m*N + n] = v;
        } else {
          if (n < 384){
            zbuf[(size_t)m*384 + n] = v;
          } else if (n < 896){
            xbcb[(size_t)m*512 + (n-384)] = v;
          } else if (n < 904){
            int hh = n - 896;
            float xx = v + dt_bias[hh];
            float dtv = (xx > 20.f) ? xx : log1pf(__expf(xx));
            int b = m >> 12, l = m & 4095;
            dtbuf[(size_t)(b*8+hh)*4096 + l] = dtv;
          }
        }
      }
}

// ------------------- K3: depthwise causal conv(4) + silu -------------------
__global__ void k_conv(const float* __restrict__ xbc, const float* __restrict__ conv_w,
                       const float* __restrict__ conv_b, float* __restrict__ xs,
                       float* __restrict__ Bm, float* __restrict__ Cm){
  int idx = blockIdx.x*256 + threadIdx.x;
  int bl = idx >> 9, c = idx & 511;
  int l = bl & 4095, b = bl >> 12;
  float acc = conv_b[c];
  #pragma unroll
  for (int k=0;k<4;k++){
    int ll = l - 3 + k;
    if (ll >= 0) acc = fmaf(conv_w[k*512+c], xbc[(size_t)(bl-3+k)*512 + c], acc);
  }
  float v = acc * sigmoidf_(acc);
  if (c < 384){
    int hh = c / 48, p = c - hh*48;
    xs[(size_t)((b*8+hh)*4096 + l)*48 + p] = v;
  } else if (c < 448){
    Bm[(size_t)bl*64 + (c-384)] = v;
  } else {
    Cm[(size_t)bl*64 + (c-448)] = v;
  }
}

// ----- K4 phase1: per-chunk cumlog(dA), chunk state T_k = sum w_s B_s x_s^T -----
__global__ __launch_bounds__(256) void k_phase1(
    const float* __restrict__ dtbuf, const float* __restrict__ Bm,
    const float* __restrict__ xs, const float* __restrict__ A_log,
    float* __restrict__ T, float* __restrict__ lac){
  __shared__ float sdt[64], sla[64], sw[64];
  __shared__ __align__(16) float sBW[64][64];
  __shared__ __align__(16) float sX[64][48];
  int tid = threadIdx.x, blk = blockIdx.x;
  int bh = blk >> 6, k = blk & 63;
  int b = bh >> 3, hh = bh & 7;
  int t0 = k*64;
  if (tid < 64) sdt[tid] = dtbuf[(size_t)bh*4096 + t0 + tid];
  __syncthreads();
  if (tid == 0){
    float eA = __expf(A_log[hh]);
    float cum = 0.f;
    for (int i=0;i<64;i++){ cum -= sdt[i]*eA; sla[i] = cum; }
  }
  __syncthreads();
  if (tid < 64){
    sw[tid] = __expf(sla[63]-sla[tid])*sdt[tid];
    lac[(size_t)blk*64 + tid] = sla[tid];
  }
  __syncthreads();
  {
    int s = tid>>2, n0 = (tid&3)*16;
    float wsc = sw[s];
    const float* src = Bm + (size_t)(b*4096 + t0 + s)*64 + n0;
    #pragma unroll
    for (int q=0;q<4;q++){
      float4 v = *(const float4*)(src + q*4);
      v.x*=wsc; v.y*=wsc; v.z*=wsc; v.w*=wsc;
      *(float4*)&sBW[s][n0+q*4] = v;
    }
    int p0 = (tid&3)*12;
    const float* xsrc = xs + (size_t)(bh*4096 + t0 + s)*48 + p0;
    #pragma unroll
    for (int q=0;q<3;q++) *(float4*)&sX[s][p0+q*4] = *(const float4*)(xsrc + q*4);
  }
  __syncthreads();
  if (tid < 192){
    int n0 = (tid/12)*4, p0 = (tid%12)*4;
    float acc[4][4];
    #pragma unroll
    for (int i=0;i<4;i++)
      #pragma unroll
      for (int j=0;j<4;j++) acc[i][j]=0.f;
    for (int s=0;s<64;s++){
      float bw[4], xv[4];
      *(float4*)bw = *(float4*)&sBW[s][n0];
      *(float4*)xv = *(float4*)&sX[s][p0];
      #pragma unroll
      for (int i=0;i<4;i++)
        #pragma unroll
        for (int j=0;j<4;j++) acc[i][j] = fmaf(bw[i], xv[j], acc[i][j]);
    }
    float* dst = T + (size_t)blk*3072;
    #pragma unroll
    for (int i=0;i<4;i++){
      float4 o; o.x=acc[i][0]; o.y=acc[i][1]; o.z=acc[i][2]; o.w=acc[i][3];
      *(float4*)(dst + (n0+i)*48 + p0) = o;
    }
  }
}

// ----- K5 phase2: sequential chunk-carry; stores S_prev per chunk -----
__global__ __launch_bounds__(384) void k_phase2(
    const float* __restrict__ T, const float* __restrict__ lac, float* __restrict__ Sp){
  __shared__ float ssc[64];
  int tid = threadIdx.x, bh = blockIdx.x, sl = blockIdx.y;
  if (tid < 64) ssc[tid] = __expf(lac[(size_t)(bh*64+tid)*64 + 63]);
  __syncthreads();
  size_t base = (size_t)bh*64*3072 + sl*384 + tid;
  float s = 0.f;
  float nv = T[base];
  for (int k=0;k<64;k++){
    float c = nv;
    if (k<63) nv = T[base + (size_t)(k+1)*3072];
    Sp[base + (size_t)k*3072] = s;
    s = fmaf(ssc[k], s, c);
  }
}

// ----- K6 phase3: Y = (L o C B^T) X + diag(exp(la)) C S_prev + D*x -----
__global__ __launch_bounds__(256, 3) void k_phase3(
    const float* __restrict__ dtbuf, const float* __restrict__ lac,
    const float* __restrict__ Bm, const float* __restrict__ Cm,
    const float* __restrict__ xs, const float* __restrict__ Sp,
    const float* __restrict__ Dparam, float* __restrict__ y){
  __shared__ __align__(16) float sBt[64][68];  // B^T [n][s] -> X [s][p]
  __shared__ __align__(16) float sCt[64][68];  // C^T [n][i]
  __shared__ __align__(16) float sSG[64][68];  // Sp [n][p] -> GM^T [s][i]
  __shared__ float sdt[64], sla[64];
  int tid = threadIdx.x, blk = blockIdx.x;
  int bh = blk>>6, k = blk&63, b = bh>>3, hh = bh&7, t0 = k*64;

  int rs = tid>>2, c0 = (tid&3)*12;
  float4 xpre0, xpre1, xpre2;
  {
    const float* xsrc = xs + (size_t)(bh*4096+t0+rs)*48 + c0;
    xpre0 = *(const float4*)(xsrc);
    xpre1 = *(const float4*)(xsrc+4);
    xpre2 = *(const float4*)(xsrc+8);
  }
  if (tid < 64){
    sdt[tid] = dtbuf[(size_t)bh*4096 + t0 + tid];
    sla[tid] = lac[(size_t)blk*64 + tid];
  }
  {
    const float* ssrc = Sp + (size_t)blk*3072 + rs*48 + c0;
    *(float4*)&sSG[rs][c0]   = *(const float4*)(ssrc);
    *(float4*)&sSG[rs][c0+4] = *(const float4*)(ssrc+4);
    *(float4*)&sSG[rs][c0+8] = *(const float4*)(ssrc+8);
  }
  {
    int s = tid>>2, n0 = (tid&3)*16;
    const float* bsrc = Bm + (size_t)(b*4096+t0+s)*64 + n0;
    const float* csrc = Cm + (size_t)(b*4096+t0+s)*64 + n0;
    #pragma unroll
    for (int q=0;q<4;q++){
      float4 bv = *(const float4*)(bsrc + q*4);
      float4 cv = *(const float4*)(csrc + q*4);
      sBt[n0+q*4+0][s]=bv.x; sBt[n0+q*4+1][s]=bv.y; sBt[n0+q*4+2][s]=bv.z; sBt[n0+q*4+3][s]=bv.w;
      sCt[n0+q*4+0][s]=cv.x; sCt[n0+q*4+1][s]=cv.y; sCt[n0+q*4+2][s]=cv.z; sCt[n0+q*4+3][s]=cv.w;
    }
  }
  __syncthreads();

  int i0p = (tid/12)*4, p0 = (tid%12)*4;
  float acc[4][4];
  #pragma unroll
  for (int i=0;i<4;i++)
    #pragma unroll
    for (int j=0;j<4;j++) acc[i][j]=0.f;
  if (tid < 192){
    #pragma unroll 4
    for (int n=0;n<64;n++){
      float cv[4], sp[4];
      *(float4*)cv = *(float4*)&sCt[n][i0p];
      *(float4*)sp = *(float4*)&sSG[n][p0];
      #pragma unroll
      for (int ii=0;ii<4;ii++)
        #pragma unroll
        for (int j=0;j<4;j++) acc[ii][j] = fmaf(cv[ii], sp[j], acc[ii][j]);
    }
  }
  int ig = (tid>>4)*4, sg = (tid&15)*4;
  float gm[4][4];
  #pragma unroll
  for (int i=0;i<4;i++)
    #pragma unroll
    for (int j=0;j<4;j++) gm[i][j]=0.f;
  if (sg <= ig+3){
    #pragma unroll 4
    for (int n=0;n<64;n++){
      float cv[4], bv[4];
      *(float4*)cv = *(float4*)&sCt[n][ig];
      *(float4*)bv = *(float4*)&sBt[n][sg];
      #pragma unroll
      for (int ii=0;ii<4;ii++)
        #pragma unroll
        for (int ss=0;ss<4;ss++) gm[ii][ss] = fmaf(cv[ii], bv[ss], gm[ii][ss]);
    }
    #pragma unroll
    for (int ii=0;ii<4;ii++)
      #pragma unroll
      for (int ss=0;ss<4;ss++){
        int i = ig+ii, s = sg+ss;
        gm[ii][ss] = (s<=i) ? gm[ii][ss]*__expf(sla[i]-sla[s])*sdt[s] : 0.f;
      }
  }
  __syncthreads();

  #pragma unroll
  for (int ss=0;ss<4;ss++){
    float4 o; o.x=gm[0][ss]; o.y=gm[1][ss]; o.z=gm[2][ss]; o.w=gm[3][ss];
    *(float4*)&sSG[sg+ss][ig] = o;
  }
  *(float4*)&sBt[rs][c0]   = xpre0;
  *(float4*)&sBt[rs][c0+4] = xpre1;
  *(float4*)&sBt[rs][c0+8] = xpre2;
  if (tid < 192){
    #pragma unroll
    for (int ii=0;ii<4;ii++){
      float ci = __expf(sla[i0p+ii]);
      #pragma unroll
      for (int j=0;j<4;j++) acc[ii][j] *= ci;
    }
  }
  __syncthreads();

  if (tid < 192){
    for (int s0=0; s0<=i0p; s0+=4){
      #pragma unroll
      for (int q=0;q<4;q++){
        float gv[4], xv[4];
        *(float4*)gv = *(float4*)&sSG[s0+q][i0p];
        *(float4*)xv = *(float4*)&sBt[s0+q][p0];
        #pragma unroll
        for (int ii=0;ii<4;ii++)
          #pragma unroll
          for (int j=0;j<4;j++) acc[ii][j] = fmaf(gv[ii], xv[j], acc[ii][j]);
      }
    }
    float Dh = Dparam[hh];
    #pragma unroll
    for (int ii=0;ii<4;ii++){
      int i = i0p+ii;
      float4 xd = *(float4*)&sBt[i][p0];
      float4 o;
      o.x = acc[ii][0] + Dh*xd.x;
      o.y = acc[ii][1] + Dh*xd.y;
      o.z = acc[ii][2] + Dh*xd.z;
      o.w = acc[ii][3] + Dh*xd.w;
      *(float4*)(y + (size_t)(b*4096+t0+i)*384 + hh*48 + p0) = o;
    }
  }
}

// ----- K7a: v = y*silu(z); RMSNorm*norm_w; emit bf16 hi/lo for out_proj -----
__global__ __launch_bounds__(384) void k_gate(
    const float* __restrict__ zbuf, const float* __restrict__ norm_w,
    const float* __restrict__ y,
    ushort_t* __restrict__ yhi, ushort_t* __restrict__ ylo){
  __shared__ float sred[6];
  __shared__ float srms;
  int bl = blockIdx.x, tid = threadIdx.x;
  float yv = y[(size_t)bl*384 + tid];
  float zv = zbuf[(size_t)bl*384 + tid];
  float g = yv * (zv * sigmoidf_(zv));
  float ss = g*g;
  #pragma unroll
  for (int off=32; off>0; off>>=1) ss += __shfl_xor(ss, off);
  if ((tid&63)==0) sred[tid>>6] = ss;
  __syncthreads();
  if (tid==0){
    float t=0.f;
    #pragma unroll
    for (int i=0;i<6;i++) t += sred[i];
    srms = rsqrtf(t*(1.f/384.f) + 1e-5f);
  }
  __syncthreads();
  float g2 = g * srms * norm_w[tid];
  ushort_t hi = f2bf(g2);
  size_t idx = (size_t)bl*384 + tid;
  yhi[idx] = hi;
  ylo[idx] = f2bf(g2 - bf2f(hi));
}

// ----- K8: MLP (192->32 relu, 32->32 relu) + partial mean accumulation -----
__global__ __launch_bounds__(256) void k_mlp(
    const float* __restrict__ h2, const float* __restrict__ W1, const float* __restrict__ b1,
    const float* __restrict__ W2, const float* __restrict__ b2, float* __restrict__ macc){
  __shared__ __align__(16) float sh2[32][192];
  __shared__ __align__(16) float sW1[192][32];
  __shared__ __align__(16) float sm1[32][32];
  __shared__ __align__(16) float sW2[32][32];
  __shared__ __align__(16) float sm2[32][32];
  int tid = threadIdx.x;
  int tok0 = blockIdx.x*32;
  int b = tok0 >> 12;
  #pragma unroll
  for (int r=0;r<6;r++){
    int e4 = tid + r*256;
    int row = e4/48, c4 = (e4%48)*4;
    *(float4*)&sh2[row][c4] = *(const float4*)(h2 + (size_t)(tok0+row)*192 + c4);
  }
  #pragma unroll
  for (int r=0;r<6;r++){
    int e4 = tid + r*256;
    int row = e4>>3, c4 = (e4&7)*4;
    *(float4*)&sW1[row][c4] = *(const float4*)(W1 + row*32 + c4);
  }
  {
    int row = tid>>3, c4 = (tid&7)*4;
    *(float4*)&sW2[row][c4] = *(const float4*)(W2 + row*32 + c4);
  }
  __syncthreads();
  {
    int tok = tid>>3, j0 = (tid&7)*4;
    float a0[4];
    #pragma unroll
    for (int j=0;j<4;j++) a0[j] = b1[j0+j];
    for (int kk=0;kk<192;kk++){
      float a = sh2[tok][kk];
      float w[4]; *(float4*)w = *(float4*)&sW1[kk][j0];
      #pragma unroll
      for (int j=0;j<4;j++) a0[j] = fmaf(a, w[j], a0[j]);
    }
    float4 o;
    o.x=fmaxf(a0[0],0.f); o.y=fmaxf(a0[1],0.f); o.z=fmaxf(a0[2],0.f); o.w=fmaxf(a0[3],0.f);
    *(float4*)&sm1[tok][j0] = o;
  }
  __syncthreads();
  {
    int tok = tid>>3, j0 = (tid&7)*4;
    float a0[4];
    #pragma unroll
    for (int j=0;j<4;j++) a0[j] = b2[j0+j];
    #pragma unroll
    for (int kk=0;kk<32;kk++){
      float a = sm1[tok][kk];
      float w[4]; *(float4*)w = *(float4*)&sW2[kk][j0];
      #pragma unroll
      for (int j=0;j<4;j++) a0[j] = fmaf(a, w[j], a0[j]);
    }
    float4 o;
    o.x=fmaxf(a0[0],0.f); o.y=fmaxf(a0[1],0.f); o.z=fmaxf(a0[2],0.f); o.w=fmaxf(a0[3],0.f);
    *(float4*)&sm2[tok][j0] = o;
  }
  __syncthreads();
  if (tid < 32){
    float t = 0.f;
    #pragma unroll
    for (int tok=0;tok<32;tok++) t += sm2[tok][tid];
    atomicAdd(&macc[b*32 + tid], t);
  }
}

// ----- K9: angle[b] = mean_m @ Wo + bo -----
__global__ void k_final(const float* __restrict__ macc, const float* __restrict__ Wo,
                        const float* __restrict__ bo, float* __restrict__ out){
  int tid = threadIdx.x;
  if (tid < 4){
    float acc = bo[0];
    #pragma unroll
    for (int j=0;j<32;j++) acc = fmaf(macc[tid*32+j]*(1.f/4096.f), Wo[j], acc);
    out[tid] = acc;
  }
}

// ---------------------------------------------------------------------------
extern "C" void kernel_launch(void* const* d_in, const int* in_sizes, int n_in,
                              void* d_out, int out_size, void* d_ws, size_t ws_size,
                              hipStream_t stream){
  const float* x      = (const float*)d_in[0];
  const float* Wfc    = (const float*)d_in[1];
  const float* bfc    = (const float*)d_in[2];
  const float* W_in   = (const float*)d_in[3];
  const float* conv_w = (const float*)d_in[4];
  const float* conv_b = (const float*)d_in[5];
  const float* dt_bias= (const float*)d_in[6];
  const float* A_log  = (const float*)d_in[7];
  const float* Dparam = (const float*)d_in[8];
  const float* norm_w = (const float*)d_in[9];
  const float* W_out  = (const float*)d_in[10];
  const float* W1     = (const float*)d_in[11];
  const float* b1     = (const float*)d_in[12];
  const float* W2     = (const float*)d_in[13];
  const float* b2     = (const float*)d_in[14];
  const float* Wo     = (const float*)d_in[15];
  const float* bo     = (const float*)d_in[16];
  float* ws  = (float*)d_ws;
  float* out = (float*)d_out;

  ushort_t* hhi = (ushort_t*)(ws + OFF_H);
  ushort_t* hlo = (ushort_t*)(ws + OFF_H) + 3145728u;      // 16384*192
  float* h2   = ws + OFF_H;                                 // reused after in_proj
  float* zb   = ws + OFF_Z;
  float* xbc  = ws + OFF_XBC;
  float* Tb   = ws + OFF_T;
  ushort_t* yhi = (ushort_t*)(ws + OFF_T);                  // reused after phase2
  ushort_t* ylo = (ushort_t*)(ws + OFF_T) + 6291456u;       // 16384*384
  float* xsb  = ws + OFF_XS;
  float* Bmb  = ws + OFF_BM;
  float* Cmb  = ws + OFF_CM;
  float* dtb  = ws + OFF_DT;
  float* lacb = ws + OFF_LAC;
  float* Spb  = ws + OFF_SP;
  ushort_t* wtih = (ushort_t*)(ws + OFF_SP);                // W_in transform (early)
  ushort_t* wtil = (ushort_t*)(ws + OFF_SP) + 196608u;      // 6*1024*32
  ushort_t* wtoh = (ushort_t*)(ws + OFF_SP);                // W_out transform (late)
  ushort_t* wtol = (ushort_t*)(ws + OFF_SP) + 73728u;       // 12*192*32
  float* yb   = ws + OFF_Y;
  float* macc = ws + OFF_MACC;

  hipMemsetAsync((void*)macc, 0, 128*sizeof(float), stream);

  k_wt<192,904,1024><<<dim3(6,4), dim3(256), 0, stream>>>(W_in, wtih, wtil);
  k_fc<<<dim3(BL), dim3(192), 0, stream>>>(x, Wfc, bfc, hhi, hlo);
  k_mgemm<192,904,1024,128,1><<<dim3(128,8), dim3(256), 0, stream>>>(
      hhi, hlo, wtih, wtil, nullptr, zb, xbc, dtb, dt_bias);
  k_conv<<<dim3(BL*512/256), dim3(256), 0, stream>>>(xbc, conv_w, conv_b, xsb, Bmb, Cmb);
  k_phase1<<<dim3(BH*NC), dim3(256), 0, stream>>>(dtb, Bmb, xsb, A_log, Tb, lacb);
  k_phase2<<<dim3(BH,8), dim3(384), 0, stream>>>(Tb, lacb, Spb);
  k_phase3<<<dim3(BH*NC), dim3(256), 0, stream>>>(dtb, lacb, Bmb, Cmb, xsb, Spb, Dparam, yb);
  k_gate<<<dim3(BL), dim3(384), 0, stream>>>(zb, norm_w, yb, yhi, ylo);
  k_wt<384,192,192><<<dim3(12,1), dim3(256), 0, stream>>>(W_out, wtoh, wtol);
  k_mgemm<384,192,192,96,0><<<dim3(128,2), dim3(256), 0, stream>>>(
      yhi, ylo, wtoh, wtol, h2, nullptr, nullptr, nullptr, nullptr);
  k_mlp<<<dim3(BL/32), dim3(256), 0, stream>>>(h2, W1, b1, W2, b2, macc);
  k_final<<<dim3(1), dim3(64), 0, stream>>>(macc, Wo, bo, out);
}